// Round 20
// baseline (769.706 us; speedup 1.0000x reference)
//
#include <hip/hip_runtime.h>

#define H 128
#define NODE_DIM 64
#define EDGE_DIM 32
#define KPRE (2*H + EDGE_DIM)   // 288
#define KPOST (13*H)            // 1664
#define T_OUT 256
#define L_DEPTH 5
#define POST_FRAGS (52*8*64)    // fragment-chunks per layer (posttrans W, permuted order)
#define Y_FRAGS (4*16*64)       // fragment-chunks per layer (ygemm W)
#define EF_FRAGS (8*64)         // fragment-chunks per layer (ef W)
#define IN_FRAGS (2*8*64)       // fragment-chunks (input W)
#define RCH 8                   // readout chunks per graph

typedef short short8v __attribute__((ext_vector_type(8)));
typedef float float4v __attribute__((ext_vector_type(4)));

__device__ __forceinline__ unsigned short f2bf(float x) {
    unsigned int b = __float_as_uint(x);
    return (unsigned short)((b + 0x7fffu + ((b >> 16) & 1u)) >> 16);  // RNE
}
__device__ __forceinline__ float bf2f(unsigned short u) {
    return __uint_as_float((unsigned int)u << 16);
}

// ---- fat pre1: degree-histogram blocks + W_in fragment-conversion blocks ----
__global__ __launch_bounds__(256) void k_pre1(
    const int* __restrict__ dst, int* __restrict__ deg_i, int E,
    const float* __restrict__ W_in, short* __restrict__ wf_in, int nHist)
{
    int tid = threadIdx.x;
    if ((int)blockIdx.x < nHist) {
        int e = blockIdx.x * 256 + tid;
        if (e < E) atomicAdd(&deg_i[dst[e]], 1);
        return;
    }
    int t = (blockIdx.x - nHist) * 256 + tid;
    if (t >= IN_FRAGS) return;
    int lane = t & 63, fc = t >> 6;
    int ks = fc >> 3, cb = fc & 7;
    int col = cb * 16 + (lane & 15);
    int k0 = ks * 32 + ((lane >> 4) << 3);
    short8v o;
#pragma unroll
    for (int j = 0; j < 8; ++j)
        o[j] = (short)f2bf(W_in[(size_t)(k0 + j) * H + col]);
    *(short8v*)(wf_in + (size_t)t * 8) = o;
}

__global__ __launch_bounds__(1024) void k_scan(const int* __restrict__ deg_i,
                                               int* __restrict__ row_start,
                                               int* __restrict__ cursor, int N) {
    __shared__ int part[1024];
    int t = threadIdx.x;
    int per = (N + 1023) / 1024;
    int base = t * per;
    int s = 0;
    for (int i = 0; i < per; ++i) {
        int idx = base + i;
        if (idx < N) s += deg_i[idx];
    }
    part[t] = s;
    __syncthreads();
    for (int off = 1; off < 1024; off <<= 1) {
        int v = (t >= off) ? part[t - off] : 0;
        __syncthreads();
        part[t] += v;
        __syncthreads();
    }
    int run = (t == 0) ? 0 : part[t - 1];
    for (int i = 0; i < per; ++i) {
        int idx = base + i;
        if (idx < N) {
            row_start[idx] = run;
            cursor[idx] = run;
            run += deg_i[idx];
        }
    }
    if (t == 1023) row_start[N] = run;
}

// ---- fat pre2: sort-scatter + weight-conversion + MFMA input-MLP ------------
__global__ __launch_bounds__(256) void k_pre2(
    const int* __restrict__ src, const int* __restrict__ dst,
    int* __restrict__ cursor, int* __restrict__ es_src,
    int* __restrict__ es_eid, int E,
    const float* __restrict__ pre_W, const float* __restrict__ post_W,
    short* __restrict__ wf_y_all, short* __restrict__ wf_post_all,
    short* __restrict__ wf_ef_all,
    const float* __restrict__ nf, const float* __restrict__ b_in,
    const short* __restrict__ wf_in, float* __restrict__ h,
    unsigned short* __restrict__ h_bf, int N, int nSort, int nWconv)
{
    __shared__ __align__(16) char smem[8192];   // MLP path only
    int tid = threadIdx.x;
    int bid = blockIdx.x;
    if (bid < nSort) {
        int e = bid * 256 + tid;
        if (e >= E) return;
        int pos = atomicAdd(&cursor[dst[e]], 1);
        es_src[pos] = src[e];
        es_eid[pos] = e;
        return;
    }
    bid -= nSort;
    if (bid < nWconv) {
        const int wrow[13] = {0, 256, 384, 512, 768, 896, 1024, 1280, 1408, 1536, 128, 640, 1152};
        int t = bid * 256 + tid;
        if (t < L_DEPTH * POST_FRAGS) {
            int l = t / POST_FRAGS, tt = t - l * POST_FRAGS;
            const float* qW = post_W + (size_t)l * KPOST * H;
            int lane = tt & 63, fc = tt >> 6;
            int b = fc >> 5, ks = (fc >> 3) & 3, cb = fc & 7;
            int col = cb * 16 + (lane & 15);
            int k0 = wrow[b] + ks * 32 + ((lane >> 4) << 3);
            short8v o;
#pragma unroll
            for (int j = 0; j < 8; ++j)
                o[j] = (short)f2bf(qW[(size_t)(k0 + j) * H + col]);
            *(short8v*)(wf_post_all + (size_t)t * 8) = o;
            return;
        }
        t -= L_DEPTH * POST_FRAGS;
        if (t < L_DEPTH * Y_FRAGS) {
            int l = t / Y_FRAGS, tt = t - l * Y_FRAGS;
            const float* pW = pre_W + (size_t)l * KPRE * H;
            int lane = tt & 63, fc = tt >> 6;
            int kglob = fc >> 4, cb = fc & 15;
            int col = cb * 16 + (lane & 15);          // 0..255
            int k0 = kglob * 32 + ((lane >> 4) << 3); // 0..127
            int rowoff = (col < 128) ? 0 : 128;
            int c = col & 127;
            short8v o;
#pragma unroll
            for (int j = 0; j < 8; ++j)
                o[j] = (short)f2bf(pW[(size_t)(rowoff + k0 + j) * H + c]);
            *(short8v*)(wf_y_all + (size_t)t * 8) = o;
            return;
        }
        t -= L_DEPTH * Y_FRAGS;
        if (t >= L_DEPTH * EF_FRAGS) return;
        int l = t / EF_FRAGS, tt = t - l * EF_FRAGS;
        int lane = tt & 63, cb = tt >> 6;             // 0..7
        int col = cb * 16 + (lane & 15);
        int k0 = (lane >> 4) << 3;
        const float* pW = pre_W + (size_t)l * KPRE * H;
        short8v o;
#pragma unroll
        for (int j = 0; j < 8; ++j)
            o[j] = (short)f2bf(pW[(size_t)(2 * H + k0 + j) * H + col]);
        *(short8v*)(wf_ef_all + (size_t)t * 8) = o;
        return;
    }
    bid -= nWconv;
    // ---- MFMA input MLP: 64 nodes/block, h = relu(nf @ W_in + b_in) ----
    short* Xs = (short*)smem;    // [64 rows][64 cols] bf16, XOR-swizzled, 8 KB
    int n0 = bid * 64;
    int lane = tid & 63, wave = tid >> 6;
    {
        int r = tid >> 2, q = tid & 3;   // row 0..63, col-quarter (16 floats)
        int n = n0 + r;
        float4 va = {}, vb = {}, vc = {}, vd = {};
        if (n < N) {
            const float* p = nf + (size_t)n * NODE_DIM + q * 16;
            va = *(const float4*)p;      vb = *(const float4*)(p + 4);
            vc = *(const float4*)(p + 8); vd = *(const float4*)(p + 12);
        }
        short8v o1, o2;
        o1[0] = (short)f2bf(va.x); o1[1] = (short)f2bf(va.y);
        o1[2] = (short)f2bf(va.z); o1[3] = (short)f2bf(va.w);
        o1[4] = (short)f2bf(vb.x); o1[5] = (short)f2bf(vb.y);
        o1[6] = (short)f2bf(vb.z); o1[7] = (short)f2bf(vb.w);
        o2[0] = (short)f2bf(vc.x); o2[1] = (short)f2bf(vc.y);
        o2[2] = (short)f2bf(vc.z); o2[3] = (short)f2bf(vc.w);
        o2[4] = (short)f2bf(vd.x); o2[5] = (short)f2bf(vd.y);
        o2[6] = (short)f2bf(vd.z); o2[7] = (short)f2bf(vd.w);
        int base = r * 128 + q * 32;
        int sw = (r & 7) << 4;
        *(short8v*)((char*)Xs + ((base) ^ sw))      = o1;
        *(short8v*)((char*)Xs + ((base + 16) ^ sw)) = o2;
    }
    __syncthreads();
    float4v acc[8];
#pragma unroll
    for (int cb = 0; cb < 8; ++cb) acc[cb] = (float4v){0.f, 0.f, 0.f, 0.f};
    int rloc = wave * 16 + (lane & 15);
    int swz = (rloc & 7) << 4;
#pragma unroll
    for (int ks = 0; ks < 2; ++ks) {
        int boff = rloc * 128 + ((ks * 64 + ((lane >> 4) << 4)) ^ swz);
        short8v a = *(short8v*)((char*)Xs + boff);
#pragma unroll
        for (int cb = 0; cb < 8; ++cb) {
            short8v b = *(const short8v*)(wf_in + ((size_t)((ks * 8 + cb) * 64 + lane)) * 8);
            acc[cb] = __builtin_amdgcn_mfma_f32_16x16x32_bf16(a, b, acc[cb], 0, 0, 0);
        }
    }
    int col0 = lane & 15;
    int row0 = wave * 16 + ((lane >> 4) << 2);
#pragma unroll
    for (int cb = 0; cb < 8; ++cb) {
        int col = cb * 16 + col0;
        float bb = b_in[col];
#pragma unroll
        for (int r = 0; r < 4; ++r) {
            int n = n0 + row0 + r;
            if (n < N) {
                float v = fmaxf(acc[cb][r] + bb, 0.f);
                h[(size_t)n * H + col] = v;
                h_bf[(size_t)n * H + col] = f2bf(v);
            }
        }
    }
}

// ---- fat pre3: ef permute blocks + scaler blocks + gbound blocks ------------
__global__ __launch_bounds__(256) void k_pre3(
    const float* __restrict__ ef, const int* __restrict__ es_eid,
    unsigned short* __restrict__ efs_bf, int E,
    const int* __restrict__ deg_i, float* __restrict__ invd,
    float* __restrict__ amp, float* __restrict__ att, int N,
    const int* __restrict__ n2g, int* __restrict__ g_start, int B,
    int nEfs, int nScal)
{
    int tid = threadIdx.x;
    int bid = blockIdx.x;
    if (bid < nEfs) {
        int t = bid * 256 + tid;
        int p = t >> 2, q = t & 3;   // 4 threads/edge, 8 ch each
        if (p >= E) return;
        int eid = es_eid[p];
        const float* sp = ef + (size_t)eid * EDGE_DIM + q * 8;
        float4 v0 = *(const float4*)sp;
        float4 v1 = *(const float4*)(sp + 4);
        short8v o;
        o[0] = (short)f2bf(v0.x); o[1] = (short)f2bf(v0.y);
        o[2] = (short)f2bf(v0.z); o[3] = (short)f2bf(v0.w);
        o[4] = (short)f2bf(v1.x); o[5] = (short)f2bf(v1.y);
        o[6] = (short)f2bf(v1.z); o[7] = (short)f2bf(v1.w);
        *(short8v*)(efs_bf + (size_t)p * EDGE_DIM + q * 8) = o;
        return;
    }
    bid -= nEfs;
    if (bid < nScal) {
        int n = bid * 256 + tid;
        if (n >= N) return;
        float d = (float)deg_i[n];
        invd[n] = (d > 0.f) ? (1.f / d) : 0.f;
        float ld = logf(d + 1.f);
        amp[n] = ld;                                 // DELTA == 1.0
        att[n] = (d > 0.f) ? (1.f / ld) : 1.f;
        return;
    }
    bid -= nScal;
    int n = bid * 256 + tid;
    if (n > N) return;
    int cur = (n < N) ? n2g[n] : B;
    int prev = (n == 0) ? -1 : n2g[n - 1];
    for (int g = prev + 1; g <= cur && g <= B; ++g)
        g_start[g] = n;
}

// ---- efw body: EFW[p][c] = efs[p] @ Wef (bf16), one block of 256 edges ------
// LDS repack writes XOR-swizzled by lane-group so the 4 row-groups hit
// disjoint bank windows (was an 8-way ds_write conflict).
__device__ __forceinline__ void efw_body(
    int blk, const unsigned short* __restrict__ efs_bf,
    const short* __restrict__ WfEf, unsigned short* __restrict__ EFW, int E,
    unsigned short (*buf)[16][128])
{
    int tid = threadIdx.x, lane = tid & 63, w = tid >> 6;
    int p0 = blk * 256 + w * 64;
    char* bw = (char*)&buf[w][0][0];
    int g5 = (lane >> 4) << 5;
    short8v bfr[8];
#pragma unroll
    for (int cb = 0; cb < 8; ++cb)
        bfr[cb] = *(const short8v*)(WfEf + (size_t)(cb * 64 + lane) * 8);
#pragma unroll
    for (int t4 = 0; t4 < 4; ++t4) {
        int rowb = p0 + t4 * 16;
        int ar = rowb + (lane & 15);
        short8v a = {};
        if (ar < E)
            a = *(const short8v*)(efs_bf + (size_t)ar * EDGE_DIM + ((lane >> 4) << 3));
        float4v acc[8];
#pragma unroll
        for (int cb = 0; cb < 8; ++cb)
            acc[cb] = __builtin_amdgcn_mfma_f32_16x16x32_bf16(
                a, bfr[cb], (float4v){0.f, 0.f, 0.f, 0.f}, 0, 0, 0);
        // repack via wave-private LDS (swizzled writes: conflict-free)
#pragma unroll
        for (int cb = 0; cb < 8; ++cb)
#pragma unroll
            for (int r = 0; r < 4; ++r) {
                int rowl = ((lane >> 4) << 2) + r;
                *(unsigned short*)(bw + rowl * 256 +
                                   (((cb * 16 + (lane & 15)) * 2) ^ g5)) = f2bf(acc[cb][r]);
            }
#pragma unroll
        for (int j = 0; j < 4; ++j) {
            int lr = (lane >> 4) + j * 4;   // lr>>2 == j
            int gr = rowb + lr;
            uint4 v = *(const uint4*)(bw + lr * 256 +
                                      ((((lane & 15) * 16)) ^ ((j & 3) << 5)));
            if (gr < E)
                *(uint4*)(EFW + (size_t)gr * H + (lane & 15) * 8) = v;
        }
    }
}

// ---- fat kernel: layer-0 Y GEMM blocks + layer-0 efw blocks (16 KB LDS union)
__global__ __launch_bounds__(256) void k_y0_fat(
    const unsigned short* __restrict__ h_bf, const short* __restrict__ Wf,
    unsigned short* __restrict__ Y1bf, unsigned short* __restrict__ Y2bf, int N,
    const unsigned short* __restrict__ efs_bf, const short* __restrict__ WfEf,
    unsigned short* __restrict__ EFW, int E, int nYBlocks)
{
    __shared__ __align__(16) char smem[16384];   // union: Xs (Y path) / buf (efw path)
    if (blockIdx.x >= nYBlocks) {
        efw_body(blockIdx.x - nYBlocks, efs_bf, WfEf, EFW, E,
                 (unsigned short (*)[16][128])smem);
        return;
    }
    short* Xs = (short*)smem;                    // 64*128 shorts = 16 KB
    int tid = threadIdx.x;
    int n0 = blockIdx.x * 64;
    int lane = tid & 63, wave = tid >> 6;
    float4v acc[16];
#pragma unroll
    for (int cb = 0; cb < 16; ++cb) acc[cb] = (float4v){0.f, 0.f, 0.f, 0.f};

    int rs = tid >> 4, c0 = (tid & 15) * 8;
#pragma unroll
    for (int j = 0; j < 4; ++j) {
        int r = rs + j * 16;
        int n = n0 + r;
        uint4 v = make_uint4(0, 0, 0, 0);
        if (n < N) v = *(const uint4*)(h_bf + (size_t)n * H + c0);
        *(uint4*)((char*)Xs + r * 256 + ((c0 * 2) ^ ((r & 7) << 4))) = v;
    }
    __syncthreads();
    int rloc = wave * 16 + (lane & 15);
    int swz = (rloc & 7) << 4;
#pragma unroll
    for (int ks = 0; ks < 4; ++ks) {
        int boff = rloc * 256 + (((ks * 64) + ((lane >> 4) << 4)) ^ swz);
        short8v a = *(short8v*)((char*)Xs + boff);
        const short* wp = Wf + ((size_t)(ks * 16) * 64 + lane) * 8;
#pragma unroll
        for (int cb = 0; cb < 16; ++cb) {
            short8v b = *(const short8v*)(wp + (size_t)cb * 512);
            acc[cb] = __builtin_amdgcn_mfma_f32_16x16x32_bf16(a, b, acc[cb], 0, 0, 0);
        }
    }
    int col0 = lane & 15;
    int row0 = wave * 16 + ((lane >> 4) << 2);
#pragma unroll
    for (int cb = 0; cb < 16; ++cb) {
        int col = cb * 16 + col0;
#pragma unroll
        for (int r = 0; r < 4; ++r) {
            int n = n0 + row0 + r;
            if (n < N) {
                if (col < 128) Y1bf[(size_t)n * H + col] = f2bf(acc[cb][r]);
                else           Y2bf[(size_t)n * H + (col - 128)] = f2bf(acc[cb][r]);
            }
        }
    }
}

// ------- aggregation: 1 wave = 1 node, 4 nodes/block, no barrier -------------
__global__ __launch_bounds__(256) void k_edge_agg(
    const unsigned short* __restrict__ Y1bf, const unsigned short* __restrict__ Y2bf,
    const unsigned short* __restrict__ EFW, const float* __restrict__ pb,
    const int* __restrict__ es_src, const int* __restrict__ row_start,
    unsigned short* __restrict__ s_out, unsigned short* __restrict__ mx_out,
    unsigned short* __restrict__ mn_out, int N)
{
    int tid = threadIdx.x, lane = tid & 63, w = tid >> 6;
    int n = blockIdx.x * 4 + w;
    if (n >= N) return;
    int start = row_start[n], end = row_start[n + 1];
    bool any = end > start;
    unsigned int y2u = *(const unsigned int*)(Y2bf + (size_t)n * H + 2 * lane);
    float2 pbv = *(const float2*)(pb + 2 * lane);
    float y20 = bf2f((unsigned short)(y2u & 0xffffu)) + pbv.x;
    float y21 = bf2f((unsigned short)(y2u >> 16)) + pbv.y;
    float s0 = 0.f, s1 = 0.f;
    float mx0 = any ? -3.4e38f : 0.f, mx1 = any ? -3.4e38f : 0.f;
    float mn0 = any ? 3.4e38f : 0.f,  mn1 = any ? 3.4e38f : 0.f;
#pragma unroll 2
    for (int p = start; p < end; ++p) {
        int sn = __builtin_amdgcn_readfirstlane(es_src[p]);
        unsigned int y1u = *(const unsigned int*)(Y1bf + (size_t)sn * H + 2 * lane);
        unsigned int eu  = *(const unsigned int*)(EFW + (size_t)p * H + 2 * lane);
        float m0 = fmaxf(bf2f((unsigned short)(y1u & 0xffffu)) +
                         bf2f((unsigned short)(eu & 0xffffu)) + y20, 0.f);
        float m1 = fmaxf(bf2f((unsigned short)(y1u >> 16)) +
                         bf2f((unsigned short)(eu >> 16)) + y21, 0.f);
        s0 += m0; s1 += m1;
        mx0 = fmaxf(mx0, m0); mx1 = fmaxf(mx1, m1);
        mn0 = fminf(mn0, m0); mn1 = fminf(mn1, m1);
    }
    size_t o = (size_t)n * H + 2 * lane;
    *(unsigned int*)(s_out + o)  = (unsigned int)f2bf(s0)  | ((unsigned int)f2bf(s1)  << 16);
    *(unsigned int*)(mx_out + o) = (unsigned int)f2bf(mx0) | ((unsigned int)f2bf(mx1) << 16);
    *(unsigned int*)(mn_out + o) = (unsigned int)f2bf(mn0) | ((unsigned int)f2bf(mn1) << 16);
}

// ------- FAT posttrans: 6-group post (+ fused Y) + efw blocks for layer l+1 ---
// out = acc0 + amp*acc1 + att*acc2 + invd*(acc3 + amp*acc4 + att*acc5)
__global__ __launch_bounds__(256) void k_post_fat(
    float* __restrict__ h, unsigned short* __restrict__ h_bf,
    const unsigned short* __restrict__ s_in, const unsigned short* __restrict__ mx_in,
    const unsigned short* __restrict__ mn_in,
    const float* __restrict__ invd, const float* __restrict__ amp,
    const float* __restrict__ att,
    const short* __restrict__ Wf, const float* __restrict__ qb,
    const short* __restrict__ WfY, unsigned short* __restrict__ Y1bf,
    unsigned short* __restrict__ Y2bf, int doY, int N,
    const unsigned short* __restrict__ efs_bf, const short* __restrict__ WfEf,
    unsigned short* __restrict__ EFW, int E, int nPostBlocks)
{
    __shared__ __align__(16) char smem[16384];   // union: Xs (post) / buf (efw)
    if (blockIdx.x >= nPostBlocks) {
        efw_body(blockIdx.x - nPostBlocks, efs_bf, WfEf, EFW, E,
                 (unsigned short (*)[16][128])smem);
        return;
    }
    short* Xs = (short*)smem;                    // 32*128 shorts = 8 KB
    int tid = threadIdx.x, lane = tid & 63, wave = tid >> 6;
    int rh = wave & 1, ch = wave >> 1;
    int n0 = blockIdx.x * 32;

    const unsigned short* const srcs[13] = {h_bf, mx_in, mn_in, s_in, mx_in, mn_in, s_in,
                                            mx_in, mn_in, s_in, s_in, s_in, s_in};
    const int grp_of[13] = {0, 0, 0, 0, 1, 1, 1, 2, 2, 2, 3, 4, 5};

    float4v acc[6][4];
#pragma unroll
    for (int g = 0; g < 6; ++g)
#pragma unroll
        for (int cb = 0; cb < 4; ++cb) acc[g][cb] = (float4v){0.f, 0.f, 0.f, 0.f};

    int arow = n0 + rh * 16 + (lane & 15);
    bool aok = arow < N;
    size_t abase = (size_t)arow * H + ((lane >> 4) << 3);

#pragma unroll
    for (int b = 0; b < 13; ++b) {
        const unsigned short* sp = srcs[b];
#pragma unroll
        for (int ks = 0; ks < 4; ++ks) {
            short8v a = {};
            if (aok) a = *(const short8v*)(sp + abase + ks * 32);
#pragma unroll
            for (int cb = 0; cb < 4; ++cb) {
                short8v bfrag = *(const short8v*)(
                    Wf + ((size_t)((b * 4 + ks) * 8 + ch * 4 + cb) * 64 + lane) * 8);
                acc[grp_of[b]][cb] =
                    __builtin_amdgcn_mfma_f32_16x16x32_bf16(a, bfrag, acc[grp_of[b]][cb], 0, 0, 0);
            }
        }
    }

    int col0 = lane & 15;
    int row0 = rh * 16 + ((lane >> 4) << 2);
    float s_invd[4], s_amp[4], s_att[4];
#pragma unroll
    for (int r = 0; r < 4; ++r) {
        int n = n0 + row0 + r;
        bool ok = n < N;
        s_invd[r] = ok ? invd[n] : 0.f;
        s_amp[r]  = ok ? amp[n]  : 0.f;
        s_att[r]  = ok ? att[n]  : 0.f;
    }
#pragma unroll
    for (int cb = 0; cb < 4; ++cb) {
        int col = (ch * 4 + cb) * 16 + col0;
        float bb = qb[col];
#pragma unroll
        for (int r = 0; r < 4; ++r) {
            int n = n0 + row0 + r;
            if (n < N) {
                float v = acc[0][cb][r]
                        + s_amp[r] * acc[1][cb][r] + s_att[r] * acc[2][cb][r]
                        + s_invd[r] * (acc[3][cb][r] + s_amp[r] * acc[4][cb][r]
                                       + s_att[r] * acc[5][cb][r]);
                size_t o = (size_t)n * H + col;
                float nv = h[o] + fmaxf(v + bb, 0.f);
                h[o] = nv;
                unsigned short us = f2bf(nv);
                h_bf[o] = us;
                if (doY) {
                    int rr = row0 + r;
                    *(short*)((char*)Xs + rr * 256 + ((col * 2) ^ ((rr & 7) << 4))) = (short)us;
                }
            }
        }
    }
    if (doY) {
        __syncthreads();
        // Y-GEMM: [32 x 128] @ [128 x 256]; wave handles cols wave*64..+63
        float4v yacc[8];
#pragma unroll
        for (int i = 0; i < 8; ++i) yacc[i] = (float4v){0.f, 0.f, 0.f, 0.f};
#pragma unroll
        for (int t16 = 0; t16 < 2; ++t16) {
            int rloc = t16 * 16 + (lane & 15);
            int swz = (rloc & 7) << 4;
#pragma unroll
            for (int ks = 0; ks < 4; ++ks) {
                int boff = rloc * 256 + (((ks * 64) + ((lane >> 4) << 4)) ^ swz);
                short8v a = *(short8v*)((char*)Xs + boff);
#pragma unroll
                for (int cb = 0; cb < 4; ++cb) {
                    const short* wp = WfY + ((size_t)(ks * 16 + wave * 4 + cb) * 64 + lane) * 8;
                    short8v b = *(const short8v*)wp;
                    yacc[t16 * 4 + cb] =
                        __builtin_amdgcn_mfma_f32_16x16x32_bf16(a, b, yacc[t16 * 4 + cb], 0, 0, 0);
                }
            }
        }
#pragma unroll
        for (int t16 = 0; t16 < 2; ++t16) {
#pragma unroll
            for (int cb = 0; cb < 4; ++cb) {
                int col = (wave * 4 + cb) * 16 + col0;
                int r0 = t16 * 16 + ((lane >> 4) << 2);
#pragma unroll
                for (int r = 0; r < 4; ++r) {
                    int n = n0 + r0 + r;
                    if (n < N) {
                        unsigned short v = f2bf(yacc[t16 * 4 + cb][r]);
                        if (col < 128) Y1bf[(size_t)n * H + col] = v;
                        else           Y2bf[(size_t)n * H + (col - 128)] = v;
                    }
                }
            }
        }
    }
}

// ------- readout stage 1: partial sum/max per (graph, chunk) — no atomics ----
__global__ __launch_bounds__(256) void k_readout_part(
    const float* __restrict__ h, const int* __restrict__ g_start,
    float* __restrict__ psum, float* __restrict__ pmax, int B)
{
    __shared__ float rs[2][128], rm[2][128];
    int blk = blockIdx.x;
    int b = blk / RCH, chunk = blk % RCH;
    int tid = threadIdx.x;
    int c = tid & 127, half = tid >> 7;
    int g0 = g_start[b], g1 = g_start[b + 1];
    int cnt = g1 - g0;
    int per = (cnt + RCH - 1) / RCH;
    int n0 = g0 + chunk * per;
    int n1 = min(n0 + per, g1);
    float s = 0.f, m = -3.4e38f;
    for (int n = n0 + half; n < n1; n += 2) {
        float v = h[(size_t)n * H + c];
        s += v;
        m = fmaxf(m, v);
    }
    rs[half][c] = s;
    rm[half][c] = m;
    __syncthreads();
    if (tid < 128) {
        size_t o = ((size_t)b * RCH + chunk) * H + c;
        psum[o] = rs[0][c] + rs[1][c];
        pmax[o] = fmaxf(rm[0][c], rm[1][c]);
    }
}

// ------- readout stage 2: combine partials + final MLP ----------------------
__global__ __launch_bounds__(256) void k_readout_final2(
    const float* __restrict__ psum, const float* __restrict__ pmax,
    const int* __restrict__ g_start,
    const float* __restrict__ W1, const float* __restrict__ b1,
    const float* __restrict__ W2, const float* __restrict__ b2,
    float* __restrict__ out)
{
    __shared__ float xv[3 * H];
    __shared__ float hid[H];
    int b = blockIdx.x, tid = threadIdx.x;
    int cnt = g_start[b + 1] - g_start[b];
    if (tid < 128) {
        int c = tid;
        float s = 0.f, m = -3.4e38f;
#pragma unroll
        for (int j = 0; j < RCH; ++j) {
            size_t o = ((size_t)b * RCH + j) * H + c;
            s += psum[o];
            m = fmaxf(m, pmax[o]);
        }
        float rc = 1.f / fmaxf((float)cnt, 1.f);
        xv[c]         = s * rc;
        xv[H + c]     = (cnt > 0) ? m : 0.f;
        xv[2 * H + c] = s;
    }
    __syncthreads();
    if (tid < 128) {
        float acc = 0.f;
        for (int k = 0; k < 3 * H; ++k)
            acc += xv[k] * W1[k * H + tid];
        hid[tid] = fmaxf(acc + b1[tid], 0.f);
    }
    __syncthreads();
    float acc = 0.f;
#pragma unroll 8
    for (int k = 0; k < H; ++k)
        acc += hid[k] * W2[k * T_OUT + tid];
    out[(size_t)b * T_OUT + tid] = acc + b2[tid];
}

extern "C" void kernel_launch(void* const* d_in, const int* in_sizes, int n_in,
                              void* d_out, int out_size, void* d_ws, size_t ws_size,
                              hipStream_t stream) {
    const float* node_feat = (const float*)d_in[0];
    const float* edge_feat = (const float*)d_in[1];
    const float* W_in  = (const float*)d_in[2];
    const float* b_in  = (const float*)d_in[3];
    const float* pre_W = (const float*)d_in[4];
    const float* pre_b = (const float*)d_in[5];
    const float* post_W = (const float*)d_in[6];
    const float* post_b = (const float*)d_in[7];
    const float* out_W1 = (const float*)d_in[8];
    const float* out_b1 = (const float*)d_in[9];
    const float* out_W2 = (const float*)d_in[10];
    const float* out_b2 = (const float*)d_in[11];
    const int* src = (const int*)d_in[12];
    const int* dst = (const int*)d_in[13];
    const int* n2g = (const int*)d_in[14];

    int N = in_sizes[0] / NODE_DIM;
    int E = in_sizes[1] / EDGE_DIM;
    int B = out_size / T_OUT;
    float* out = (float*)d_out;

    float* ws = (float*)d_ws;
    float* h    = ws; ws += (size_t)N * H;
    float* invd = ws; ws += N;
    float* amp  = ws; ws += N;
    float* att  = ws; ws += N;
    float* psum = ws; ws += (size_t)B * RCH * H;
    float* pmax = ws; ws += (size_t)B * RCH * H;
    ws = (float*)(((uintptr_t)ws + 15) & ~(uintptr_t)15);
    unsigned short* h_bf  = (unsigned short*)ws;
    unsigned short* s_buf = h_bf  + (size_t)N * H;
    unsigned short* mx    = s_buf + (size_t)N * H;
    unsigned short* mn    = mx    + (size_t)N * H;
    unsigned short* Y1bf  = mn    + (size_t)N * H;
    unsigned short* Y2bf  = Y1bf  + (size_t)N * H;
    unsigned short* efs_bf = Y2bf + (size_t)N * H;
    unsigned short* EFW    = efs_bf + (size_t)E * EDGE_DIM;
    short* wf_post_all = (short*)(EFW + (size_t)E * H);
    short* wf_y_all    = wf_post_all + (size_t)L_DEPTH * POST_FRAGS * 8;
    short* wf_ef_all   = wf_y_all + (size_t)L_DEPTH * Y_FRAGS * 8;
    short* wf_in       = wf_ef_all + (size_t)L_DEPTH * EF_FRAGS * 8;
    int* deg_i     = (int*)(wf_in + (size_t)IN_FRAGS * 8);
    int* row_start = deg_i + N;
    int* cursor    = row_start + N + 1;
    int* es_src    = cursor + N;
    int* es_eid    = es_src + E;
    int* g_start   = es_eid + E;   // B+1 ints

    int nPostBlocks = (N + 31) / 32;
    int nEfBlocks   = (E + 255) / 256;
    int nYBlocks    = (N + 63) / 64;
    int nHistBlocks = (E + 255) / 256;
    int nWinBlocks  = (IN_FRAGS + 255) / 256;
    int nSortBlocks = (E + 255) / 256;
    int nWconvBlocks = (L_DEPTH * (POST_FRAGS + Y_FRAGS + EF_FRAGS) + 255) / 256;
    int nMlpBlocks  = (N + 63) / 64;
    int nEfsBlocks  = ((size_t)E * 4 + 255) / 256;
    int nScalBlocks = (N + 255) / 256;
    int nGbBlocks   = (N + 1 + 255) / 256;

    // pre1: degree histogram + W_in fragment conversion (fat)
    hipMemsetAsync(deg_i, 0, (size_t)N * sizeof(int), stream);
    k_pre1<<<nHistBlocks + nWinBlocks, 256, 0, stream>>>(
        dst, deg_i, E, W_in, wf_in, nHistBlocks);

    // scan (single block)
    k_scan<<<1, 1024, 0, stream>>>(deg_i, row_start, cursor, N);

    // pre2: sort-scatter + all-layer weight conversion + MFMA input MLP (fat)
    k_pre2<<<nSortBlocks + nWconvBlocks + nMlpBlocks, 256, 0, stream>>>(
        src, dst, cursor, es_src, es_eid, E,
        pre_W, post_W, wf_y_all, wf_post_all, wf_ef_all,
        node_feat, b_in, wf_in, h, h_bf, N, nSortBlocks, nWconvBlocks);

    // pre3: ef permute + scalers + graph bounds (fat)
    k_pre3<<<nEfsBlocks + nScalBlocks + nGbBlocks, 256, 0, stream>>>(
        edge_feat, es_eid, efs_bf, E, deg_i, invd, amp, att, N,
        n2g, g_start, B, nEfsBlocks, nScalBlocks);

    // fat: layer-0 Y GEMM + layer-0 efw in one dispatch
    k_y0_fat<<<nYBlocks + nEfBlocks, 256, 0, stream>>>(
        h_bf, wf_y_all, Y1bf, Y2bf, N, efs_bf, wf_ef_all, EFW, E, nYBlocks);

    for (int l = 0; l < L_DEPTH; ++l) {
        k_edge_agg<<<(N + 3) / 4, 256, 0, stream>>>(
            Y1bf, Y2bf, EFW, pre_b + (size_t)l * H,
            es_src, row_start, s_buf, mx, mn, N);
        int doY = (l < L_DEPTH - 1) ? 1 : 0;
        int grid = nPostBlocks + (doY ? nEfBlocks : 0);
        k_post_fat<<<grid, 256, 0, stream>>>(
            h, h_bf, s_buf, mx, mn, invd, amp, att,
            wf_post_all + (size_t)l * POST_FRAGS * 8, post_b + (size_t)l * H,
            doY ? (wf_y_all + (size_t)(l + 1) * Y_FRAGS * 8) : wf_y_all,
            Y1bf, Y2bf, doY, N,
            efs_bf, doY ? (wf_ef_all + (size_t)(l + 1) * EF_FRAGS * 8) : wf_ef_all,
            EFW, E, nPostBlocks);
    }

    // two-stage readout (no atomics; n2g is sorted) + final MLP
    k_readout_part<<<B * RCH, 256, 0, stream>>>(h, g_start, psum, pmax, B);
    k_readout_final2<<<B, 256, 0, stream>>>(psum, pmax, g_start,
                                            out_W1, out_b1, out_W2, out_b2, out);
}

// Round 21
// 611.556 us; speedup vs baseline: 1.2586x; 1.2586x over previous
//
#include <hip/hip_runtime.h>

#define H 128
#define NODE_DIM 64
#define EDGE_DIM 32
#define KPRE (2*H + EDGE_DIM)   // 288
#define KPOST (13*H)            // 1664
#define T_OUT 256
#define L_DEPTH 5
#define POST_FRAGS (52*8*64)    // fragment-chunks per layer (posttrans W, permuted order)
#define Y_FRAGS (4*16*64)       // fragment-chunks per layer (ygemm W)
#define EF_FRAGS (8*64)         // fragment-chunks per layer (ef W)
#define IN_FRAGS (2*8*64)       // fragment-chunks (input W)
#define RCH 8                   // readout chunks per graph

typedef short short8v __attribute__((ext_vector_type(8)));
typedef float float4v __attribute__((ext_vector_type(4)));

__device__ __forceinline__ unsigned short f2bf(float x) {
    unsigned int b = __float_as_uint(x);
    return (unsigned short)((b + 0x7fffu + ((b >> 16) & 1u)) >> 16);  // RNE
}
__device__ __forceinline__ float bf2f(unsigned short u) {
    return __uint_as_float((unsigned int)u << 16);
}

// ---- fat pre1: degree-histogram blocks + W_in fragment-conversion blocks ----
__global__ __launch_bounds__(256) void k_pre1(
    const int* __restrict__ dst, int* __restrict__ deg_i, int E,
    const float* __restrict__ W_in, short* __restrict__ wf_in, int nHist)
{
    int tid = threadIdx.x;
    if ((int)blockIdx.x < nHist) {
        int e = blockIdx.x * 256 + tid;
        if (e < E) atomicAdd(&deg_i[dst[e]], 1);
        return;
    }
    int t = (blockIdx.x - nHist) * 256 + tid;
    if (t >= IN_FRAGS) return;
    int lane = t & 63, fc = t >> 6;
    int ks = fc >> 3, cb = fc & 7;
    int col = cb * 16 + (lane & 15);
    int k0 = ks * 32 + ((lane >> 4) << 3);
    short8v o;
#pragma unroll
    for (int j = 0; j < 8; ++j)
        o[j] = (short)f2bf(W_in[(size_t)(k0 + j) * H + col]);
    *(short8v*)(wf_in + (size_t)t * 8) = o;
}

__global__ __launch_bounds__(1024) void k_scan(const int* __restrict__ deg_i,
                                               int* __restrict__ row_start,
                                               int* __restrict__ cursor, int N) {
    __shared__ int part[1024];
    int t = threadIdx.x;
    int per = (N + 1023) / 1024;
    int base = t * per;
    int s = 0;
    for (int i = 0; i < per; ++i) {
        int idx = base + i;
        if (idx < N) s += deg_i[idx];
    }
    part[t] = s;
    __syncthreads();
    for (int off = 1; off < 1024; off <<= 1) {
        int v = (t >= off) ? part[t - off] : 0;
        __syncthreads();
        part[t] += v;
        __syncthreads();
    }
    int run = (t == 0) ? 0 : part[t - 1];
    for (int i = 0; i < per; ++i) {
        int idx = base + i;
        if (idx < N) {
            row_start[idx] = run;
            cursor[idx] = run;
            run += deg_i[idx];
        }
    }
    if (t == 1023) row_start[N] = run;
}

// ---- fat pre2: sort-scatter + weight-conversion + MFMA input-MLP ------------
__global__ __launch_bounds__(256) void k_pre2(
    const int* __restrict__ src, const int* __restrict__ dst,
    int* __restrict__ cursor, int* __restrict__ es_src,
    int* __restrict__ es_eid, int E,
    const float* __restrict__ pre_W, const float* __restrict__ post_W,
    short* __restrict__ wf_y_all, short* __restrict__ wf_post_all,
    short* __restrict__ wf_ef_all,
    const float* __restrict__ nf, const float* __restrict__ b_in,
    const short* __restrict__ wf_in, float* __restrict__ h,
    unsigned short* __restrict__ h_bf, int N, int nSort, int nWconv)
{
    __shared__ __align__(16) char smem[8192];   // MLP path only
    int tid = threadIdx.x;
    int bid = blockIdx.x;
    if (bid < nSort) {
        int e = bid * 256 + tid;
        if (e >= E) return;
        int pos = atomicAdd(&cursor[dst[e]], 1);
        es_src[pos] = src[e];
        es_eid[pos] = e;
        return;
    }
    bid -= nSort;
    if (bid < nWconv) {
        const int wrow[13] = {0, 256, 384, 512, 768, 896, 1024, 1280, 1408, 1536, 128, 640, 1152};
        int t = bid * 256 + tid;
        if (t < L_DEPTH * POST_FRAGS) {
            int l = t / POST_FRAGS, tt = t - l * POST_FRAGS;
            const float* qW = post_W + (size_t)l * KPOST * H;
            int lane = tt & 63, fc = tt >> 6;
            int b = fc >> 5, ks = (fc >> 3) & 3, cb = fc & 7;
            int col = cb * 16 + (lane & 15);
            int k0 = wrow[b] + ks * 32 + ((lane >> 4) << 3);
            short8v o;
#pragma unroll
            for (int j = 0; j < 8; ++j)
                o[j] = (short)f2bf(qW[(size_t)(k0 + j) * H + col]);
            *(short8v*)(wf_post_all + (size_t)t * 8) = o;
            return;
        }
        t -= L_DEPTH * POST_FRAGS;
        if (t < L_DEPTH * Y_FRAGS) {
            int l = t / Y_FRAGS, tt = t - l * Y_FRAGS;
            const float* pW = pre_W + (size_t)l * KPRE * H;
            int lane = tt & 63, fc = tt >> 6;
            int kglob = fc >> 4, cb = fc & 15;
            int col = cb * 16 + (lane & 15);          // 0..255
            int k0 = kglob * 32 + ((lane >> 4) << 3); // 0..127
            int rowoff = (col < 128) ? 0 : 128;
            int c = col & 127;
            short8v o;
#pragma unroll
            for (int j = 0; j < 8; ++j)
                o[j] = (short)f2bf(pW[(size_t)(rowoff + k0 + j) * H + c]);
            *(short8v*)(wf_y_all + (size_t)t * 8) = o;
            return;
        }
        t -= L_DEPTH * Y_FRAGS;
        if (t >= L_DEPTH * EF_FRAGS) return;
        int l = t / EF_FRAGS, tt = t - l * EF_FRAGS;
        int lane = tt & 63, cb = tt >> 6;             // 0..7
        int col = cb * 16 + (lane & 15);
        int k0 = (lane >> 4) << 3;
        const float* pW = pre_W + (size_t)l * KPRE * H;
        short8v o;
#pragma unroll
        for (int j = 0; j < 8; ++j)
            o[j] = (short)f2bf(pW[(size_t)(2 * H + k0 + j) * H + col]);
        *(short8v*)(wf_ef_all + (size_t)t * 8) = o;
        return;
    }
    bid -= nWconv;
    // ---- MFMA input MLP: 64 nodes/block, h = relu(nf @ W_in + b_in) ----
    short* Xs = (short*)smem;    // [64 rows][64 cols] bf16, XOR-swizzled, 8 KB
    int n0 = bid * 64;
    int lane = tid & 63, wave = tid >> 6;
    {
        int r = tid >> 2, q = tid & 3;   // row 0..63, col-quarter (16 floats)
        int n = n0 + r;
        float4 va = {}, vb = {}, vc = {}, vd = {};
        if (n < N) {
            const float* p = nf + (size_t)n * NODE_DIM + q * 16;
            va = *(const float4*)p;      vb = *(const float4*)(p + 4);
            vc = *(const float4*)(p + 8); vd = *(const float4*)(p + 12);
        }
        short8v o1, o2;
        o1[0] = (short)f2bf(va.x); o1[1] = (short)f2bf(va.y);
        o1[2] = (short)f2bf(va.z); o1[3] = (short)f2bf(va.w);
        o1[4] = (short)f2bf(vb.x); o1[5] = (short)f2bf(vb.y);
        o1[6] = (short)f2bf(vb.z); o1[7] = (short)f2bf(vb.w);
        o2[0] = (short)f2bf(vc.x); o2[1] = (short)f2bf(vc.y);
        o2[2] = (short)f2bf(vc.z); o2[3] = (short)f2bf(vc.w);
        o2[4] = (short)f2bf(vd.x); o2[5] = (short)f2bf(vd.y);
        o2[6] = (short)f2bf(vd.z); o2[7] = (short)f2bf(vd.w);
        int base = r * 128 + q * 32;
        int sw = (r & 7) << 4;
        *(short8v*)((char*)Xs + ((base) ^ sw))      = o1;
        *(short8v*)((char*)Xs + ((base + 16) ^ sw)) = o2;
    }
    __syncthreads();
    float4v acc[8];
#pragma unroll
    for (int cb = 0; cb < 8; ++cb) acc[cb] = (float4v){0.f, 0.f, 0.f, 0.f};
    int rloc = wave * 16 + (lane & 15);
    int swz = (rloc & 7) << 4;
#pragma unroll
    for (int ks = 0; ks < 2; ++ks) {
        int boff = rloc * 128 + ((ks * 64 + ((lane >> 4) << 4)) ^ swz);
        short8v a = *(short8v*)((char*)Xs + boff);
#pragma unroll
        for (int cb = 0; cb < 8; ++cb) {
            short8v b = *(const short8v*)(wf_in + ((size_t)((ks * 8 + cb) * 64 + lane)) * 8);
            acc[cb] = __builtin_amdgcn_mfma_f32_16x16x32_bf16(a, b, acc[cb], 0, 0, 0);
        }
    }
    int col0 = lane & 15;
    int row0 = wave * 16 + ((lane >> 4) << 2);
#pragma unroll
    for (int cb = 0; cb < 8; ++cb) {
        int col = cb * 16 + col0;
        float bb = b_in[col];
#pragma unroll
        for (int r = 0; r < 4; ++r) {
            int n = n0 + row0 + r;
            if (n < N) {
                float v = fmaxf(acc[cb][r] + bb, 0.f);
                h[(size_t)n * H + col] = v;
                h_bf[(size_t)n * H + col] = f2bf(v);
            }
        }
    }
}

// ---- fat pre3: ef permute blocks + scaler blocks + gbound blocks ------------
__global__ __launch_bounds__(256) void k_pre3(
    const float* __restrict__ ef, const int* __restrict__ es_eid,
    unsigned short* __restrict__ efs_bf, int E,
    const int* __restrict__ deg_i, float* __restrict__ invd,
    float* __restrict__ amp, float* __restrict__ att, int N,
    const int* __restrict__ n2g, int* __restrict__ g_start, int B,
    int nEfs, int nScal)
{
    int tid = threadIdx.x;
    int bid = blockIdx.x;
    if (bid < nEfs) {
        int t = bid * 256 + tid;
        int p = t >> 2, q = t & 3;   // 4 threads/edge, 8 ch each
        if (p >= E) return;
        int eid = es_eid[p];
        const float* sp = ef + (size_t)eid * EDGE_DIM + q * 8;
        float4 v0 = *(const float4*)sp;
        float4 v1 = *(const float4*)(sp + 4);
        short8v o;
        o[0] = (short)f2bf(v0.x); o[1] = (short)f2bf(v0.y);
        o[2] = (short)f2bf(v0.z); o[3] = (short)f2bf(v0.w);
        o[4] = (short)f2bf(v1.x); o[5] = (short)f2bf(v1.y);
        o[6] = (short)f2bf(v1.z); o[7] = (short)f2bf(v1.w);
        *(short8v*)(efs_bf + (size_t)p * EDGE_DIM + q * 8) = o;
        return;
    }
    bid -= nEfs;
    if (bid < nScal) {
        int n = bid * 256 + tid;
        if (n >= N) return;
        float d = (float)deg_i[n];
        invd[n] = (d > 0.f) ? (1.f / d) : 0.f;
        float ld = logf(d + 1.f);
        amp[n] = ld;                                 // DELTA == 1.0
        att[n] = (d > 0.f) ? (1.f / ld) : 1.f;
        return;
    }
    bid -= nScal;
    int n = bid * 256 + tid;
    if (n > N) return;
    int cur = (n < N) ? n2g[n] : B;
    int prev = (n == 0) ? -1 : n2g[n - 1];
    for (int g = prev + 1; g <= cur && g <= B; ++g)
        g_start[g] = n;
}

// ---- efw body: EFW[p][c] = efs[p] @ Wef (bf16), one block of 256 edges ------
__device__ __forceinline__ void efw_body(
    int blk, const unsigned short* __restrict__ efs_bf,
    const short* __restrict__ WfEf, unsigned short* __restrict__ EFW, int E,
    unsigned short (*buf)[16][128])
{
    int tid = threadIdx.x, lane = tid & 63, w = tid >> 6;
    int p0 = blk * 256 + w * 64;
    short8v bfr[8];
#pragma unroll
    for (int cb = 0; cb < 8; ++cb)
        bfr[cb] = *(const short8v*)(WfEf + (size_t)(cb * 64 + lane) * 8);
#pragma unroll
    for (int t4 = 0; t4 < 4; ++t4) {
        int rowb = p0 + t4 * 16;
        int ar = rowb + (lane & 15);
        short8v a = {};
        if (ar < E)
            a = *(const short8v*)(efs_bf + (size_t)ar * EDGE_DIM + ((lane >> 4) << 3));
        float4v acc[8];
#pragma unroll
        for (int cb = 0; cb < 8; ++cb)
            acc[cb] = __builtin_amdgcn_mfma_f32_16x16x32_bf16(
                a, bfr[cb], (float4v){0.f, 0.f, 0.f, 0.f}, 0, 0, 0);
        // repack via wave-private LDS (DS ops are in-order per wave)
#pragma unroll
        for (int cb = 0; cb < 8; ++cb)
#pragma unroll
            for (int r = 0; r < 4; ++r)
                buf[w][((lane >> 4) << 2) + r][cb * 16 + (lane & 15)] = f2bf(acc[cb][r]);
#pragma unroll
        for (int j = 0; j < 4; ++j) {
            int lr = (lane >> 4) + j * 4;
            int gr = rowb + lr;
            uint4 v = *(const uint4*)&buf[w][lr][(lane & 15) * 8];
            if (gr < E)
                *(uint4*)(EFW + (size_t)gr * H + (lane & 15) * 8) = v;
        }
    }
}

// ---- fat kernel: layer-0 Y GEMM blocks + layer-0 efw blocks (16 KB LDS union)
__global__ __launch_bounds__(256) void k_y0_fat(
    const unsigned short* __restrict__ h_bf, const short* __restrict__ Wf,
    unsigned short* __restrict__ Y1bf, unsigned short* __restrict__ Y2bf, int N,
    const unsigned short* __restrict__ efs_bf, const short* __restrict__ WfEf,
    unsigned short* __restrict__ EFW, int E, int nYBlocks)
{
    __shared__ __align__(16) char smem[16384];   // union: Xs (Y path) / buf (efw path)
    if (blockIdx.x >= nYBlocks) {
        efw_body(blockIdx.x - nYBlocks, efs_bf, WfEf, EFW, E,
                 (unsigned short (*)[16][128])smem);
        return;
    }
    short* Xs = (short*)smem;                    // 64*128 shorts = 16 KB
    int tid = threadIdx.x;
    int n0 = blockIdx.x * 64;
    int lane = tid & 63, wave = tid >> 6;
    float4v acc[16];
#pragma unroll
    for (int cb = 0; cb < 16; ++cb) acc[cb] = (float4v){0.f, 0.f, 0.f, 0.f};

    int rs = tid >> 4, c0 = (tid & 15) * 8;
#pragma unroll
    for (int j = 0; j < 4; ++j) {
        int r = rs + j * 16;
        int n = n0 + r;
        uint4 v = make_uint4(0, 0, 0, 0);
        if (n < N) v = *(const uint4*)(h_bf + (size_t)n * H + c0);
        *(uint4*)((char*)Xs + r * 256 + ((c0 * 2) ^ ((r & 7) << 4))) = v;
    }
    __syncthreads();
    int rloc = wave * 16 + (lane & 15);
    int swz = (rloc & 7) << 4;
#pragma unroll
    for (int ks = 0; ks < 4; ++ks) {
        int boff = rloc * 256 + (((ks * 64) + ((lane >> 4) << 4)) ^ swz);
        short8v a = *(short8v*)((char*)Xs + boff);
        const short* wp = Wf + ((size_t)(ks * 16) * 64 + lane) * 8;
#pragma unroll
        for (int cb = 0; cb < 16; ++cb) {
            short8v b = *(const short8v*)(wp + (size_t)cb * 512);
            acc[cb] = __builtin_amdgcn_mfma_f32_16x16x32_bf16(a, b, acc[cb], 0, 0, 0);
        }
    }
    int col0 = lane & 15;
    int row0 = wave * 16 + ((lane >> 4) << 2);
#pragma unroll
    for (int cb = 0; cb < 16; ++cb) {
        int col = cb * 16 + col0;
#pragma unroll
        for (int r = 0; r < 4; ++r) {
            int n = n0 + row0 + r;
            if (n < N) {
                if (col < 128) Y1bf[(size_t)n * H + col] = f2bf(acc[cb][r]);
                else           Y2bf[(size_t)n * H + (col - 128)] = f2bf(acc[cb][r]);
            }
        }
    }
}

// ------- aggregation: 1 wave = 1 node, 4 nodes/block, no barrier -------------
__global__ __launch_bounds__(256) void k_edge_agg(
    const unsigned short* __restrict__ Y1bf, const unsigned short* __restrict__ Y2bf,
    const unsigned short* __restrict__ EFW, const float* __restrict__ pb,
    const int* __restrict__ es_src, const int* __restrict__ row_start,
    unsigned short* __restrict__ s_out, unsigned short* __restrict__ mx_out,
    unsigned short* __restrict__ mn_out, int N)
{
    int tid = threadIdx.x, lane = tid & 63, w = tid >> 6;
    int n = blockIdx.x * 4 + w;
    if (n >= N) return;
    int start = row_start[n], end = row_start[n + 1];
    bool any = end > start;
    unsigned int y2u = *(const unsigned int*)(Y2bf + (size_t)n * H + 2 * lane);
    float2 pbv = *(const float2*)(pb + 2 * lane);
    float y20 = bf2f((unsigned short)(y2u & 0xffffu)) + pbv.x;
    float y21 = bf2f((unsigned short)(y2u >> 16)) + pbv.y;
    float s0 = 0.f, s1 = 0.f;
    float mx0 = any ? -3.4e38f : 0.f, mx1 = any ? -3.4e38f : 0.f;
    float mn0 = any ? 3.4e38f : 0.f,  mn1 = any ? 3.4e38f : 0.f;
#pragma unroll 2
    for (int p = start; p < end; ++p) {
        int sn = __builtin_amdgcn_readfirstlane(es_src[p]);
        unsigned int y1u = *(const unsigned int*)(Y1bf + (size_t)sn * H + 2 * lane);
        unsigned int eu  = *(const unsigned int*)(EFW + (size_t)p * H + 2 * lane);
        float m0 = fmaxf(bf2f((unsigned short)(y1u & 0xffffu)) +
                         bf2f((unsigned short)(eu & 0xffffu)) + y20, 0.f);
        float m1 = fmaxf(bf2f((unsigned short)(y1u >> 16)) +
                         bf2f((unsigned short)(eu >> 16)) + y21, 0.f);
        s0 += m0; s1 += m1;
        mx0 = fmaxf(mx0, m0); mx1 = fmaxf(mx1, m1);
        mn0 = fminf(mn0, m0); mn1 = fminf(mn1, m1);
    }
    size_t o = (size_t)n * H + 2 * lane;
    *(unsigned int*)(s_out + o)  = (unsigned int)f2bf(s0)  | ((unsigned int)f2bf(s1)  << 16);
    *(unsigned int*)(mx_out + o) = (unsigned int)f2bf(mx0) | ((unsigned int)f2bf(mx1) << 16);
    *(unsigned int*)(mn_out + o) = (unsigned int)f2bf(mn0) | ((unsigned int)f2bf(mn1) << 16);
}

// ------- FAT posttrans: 6-group post (+ fused Y) + efw blocks for layer l+1 ---
// out = acc0 + amp*acc1 + att*acc2 + invd*(acc3 + amp*acc4 + att*acc5)
__global__ __launch_bounds__(256) void k_post_fat(
    float* __restrict__ h, unsigned short* __restrict__ h_bf,
    const unsigned short* __restrict__ s_in, const unsigned short* __restrict__ mx_in,
    const unsigned short* __restrict__ mn_in,
    const float* __restrict__ invd, const float* __restrict__ amp,
    const float* __restrict__ att,
    const short* __restrict__ Wf, const float* __restrict__ qb,
    const short* __restrict__ WfY, unsigned short* __restrict__ Y1bf,
    unsigned short* __restrict__ Y2bf, int doY, int N,
    const unsigned short* __restrict__ efs_bf, const short* __restrict__ WfEf,
    unsigned short* __restrict__ EFW, int E, int nPostBlocks)
{
    __shared__ __align__(16) char smem[16384];   // union: Xs (post) / buf (efw)
    if (blockIdx.x >= nPostBlocks) {
        efw_body(blockIdx.x - nPostBlocks, efs_bf, WfEf, EFW, E,
                 (unsigned short (*)[16][128])smem);
        return;
    }
    short* Xs = (short*)smem;                    // 32*128 shorts = 8 KB
    int tid = threadIdx.x, lane = tid & 63, wave = tid >> 6;
    int rh = wave & 1, ch = wave >> 1;
    int n0 = blockIdx.x * 32;

    const unsigned short* const srcs[13] = {h_bf, mx_in, mn_in, s_in, mx_in, mn_in, s_in,
                                            mx_in, mn_in, s_in, s_in, s_in, s_in};
    const int grp_of[13] = {0, 0, 0, 0, 1, 1, 1, 2, 2, 2, 3, 4, 5};

    float4v acc[6][4];
#pragma unroll
    for (int g = 0; g < 6; ++g)
#pragma unroll
        for (int cb = 0; cb < 4; ++cb) acc[g][cb] = (float4v){0.f, 0.f, 0.f, 0.f};

    int arow = n0 + rh * 16 + (lane & 15);
    bool aok = arow < N;
    size_t abase = (size_t)arow * H + ((lane >> 4) << 3);

#pragma unroll
    for (int b = 0; b < 13; ++b) {
        const unsigned short* sp = srcs[b];
#pragma unroll
        for (int ks = 0; ks < 4; ++ks) {
            short8v a = {};
            if (aok) a = *(const short8v*)(sp + abase + ks * 32);
#pragma unroll
            for (int cb = 0; cb < 4; ++cb) {
                short8v bfrag = *(const short8v*)(
                    Wf + ((size_t)((b * 4 + ks) * 8 + ch * 4 + cb) * 64 + lane) * 8);
                acc[grp_of[b]][cb] =
                    __builtin_amdgcn_mfma_f32_16x16x32_bf16(a, bfrag, acc[grp_of[b]][cb], 0, 0, 0);
            }
        }
    }

    int col0 = lane & 15;
    int row0 = rh * 16 + ((lane >> 4) << 2);
    float s_invd[4], s_amp[4], s_att[4];
#pragma unroll
    for (int r = 0; r < 4; ++r) {
        int n = n0 + row0 + r;
        bool ok = n < N;
        s_invd[r] = ok ? invd[n] : 0.f;
        s_amp[r]  = ok ? amp[n]  : 0.f;
        s_att[r]  = ok ? att[n]  : 0.f;
    }
#pragma unroll
    for (int cb = 0; cb < 4; ++cb) {
        int col = (ch * 4 + cb) * 16 + col0;
        float bb = qb[col];
#pragma unroll
        for (int r = 0; r < 4; ++r) {
            int n = n0 + row0 + r;
            if (n < N) {
                float v = acc[0][cb][r]
                        + s_amp[r] * acc[1][cb][r] + s_att[r] * acc[2][cb][r]
                        + s_invd[r] * (acc[3][cb][r] + s_amp[r] * acc[4][cb][r]
                                       + s_att[r] * acc[5][cb][r]);
                size_t o = (size_t)n * H + col;
                float nv = h[o] + fmaxf(v + bb, 0.f);
                h[o] = nv;
                unsigned short us = f2bf(nv);
                h_bf[o] = us;
                if (doY) {
                    int rr = row0 + r;
                    *(short*)((char*)Xs + rr * 256 + ((col * 2) ^ ((rr & 7) << 4))) = (short)us;
                }
            }
        }
    }
    if (doY) {
        __syncthreads();
        // Y-GEMM: [32 x 128] @ [128 x 256]; wave handles cols wave*64..+63
        float4v yacc[8];
#pragma unroll
        for (int i = 0; i < 8; ++i) yacc[i] = (float4v){0.f, 0.f, 0.f, 0.f};
#pragma unroll
        for (int t16 = 0; t16 < 2; ++t16) {
            int rloc = t16 * 16 + (lane & 15);
            int swz = (rloc & 7) << 4;
#pragma unroll
            for (int ks = 0; ks < 4; ++ks) {
                int boff = rloc * 256 + (((ks * 64) + ((lane >> 4) << 4)) ^ swz);
                short8v a = *(short8v*)((char*)Xs + boff);
#pragma unroll
                for (int cb = 0; cb < 4; ++cb) {
                    const short* wp = WfY + ((size_t)(ks * 16 + wave * 4 + cb) * 64 + lane) * 8;
                    short8v b = *(const short8v*)wp;
                    yacc[t16 * 4 + cb] =
                        __builtin_amdgcn_mfma_f32_16x16x32_bf16(a, b, yacc[t16 * 4 + cb], 0, 0, 0);
                }
            }
        }
#pragma unroll
        for (int t16 = 0; t16 < 2; ++t16) {
#pragma unroll
            for (int cb = 0; cb < 4; ++cb) {
                int col = (wave * 4 + cb) * 16 + col0;
                int r0 = t16 * 16 + ((lane >> 4) << 2);
#pragma unroll
                for (int r = 0; r < 4; ++r) {
                    int n = n0 + r0 + r;
                    if (n < N) {
                        unsigned short v = f2bf(yacc[t16 * 4 + cb][r]);
                        if (col < 128) Y1bf[(size_t)n * H + col] = v;
                        else           Y2bf[(size_t)n * H + (col - 128)] = v;
                    }
                }
            }
        }
    }
}

// ------- readout stage 1: partial sum/max per (graph, chunk) — no atomics ----
__global__ __launch_bounds__(256) void k_readout_part(
    const float* __restrict__ h, const int* __restrict__ g_start,
    float* __restrict__ psum, float* __restrict__ pmax, int B)
{
    __shared__ float rs[2][128], rm[2][128];
    int blk = blockIdx.x;
    int b = blk / RCH, chunk = blk % RCH;
    int tid = threadIdx.x;
    int c = tid & 127, half = tid >> 7;
    int g0 = g_start[b], g1 = g_start[b + 1];
    int cnt = g1 - g0;
    int per = (cnt + RCH - 1) / RCH;
    int n0 = g0 + chunk * per;
    int n1 = min(n0 + per, g1);
    float s = 0.f, m = -3.4e38f;
    for (int n = n0 + half; n < n1; n += 2) {
        float v = h[(size_t)n * H + c];
        s += v;
        m = fmaxf(m, v);
    }
    rs[half][c] = s;
    rm[half][c] = m;
    __syncthreads();
    if (tid < 128) {
        size_t o = ((size_t)b * RCH + chunk) * H + c;
        psum[o] = rs[0][c] + rs[1][c];
        pmax[o] = fmaxf(rm[0][c], rm[1][c]);
    }
}

// ------- readout stage 2: combine partials + final MLP ----------------------
__global__ __launch_bounds__(256) void k_readout_final2(
    const float* __restrict__ psum, const float* __restrict__ pmax,
    const int* __restrict__ g_start,
    const float* __restrict__ W1, const float* __restrict__ b1,
    const float* __restrict__ W2, const float* __restrict__ b2,
    float* __restrict__ out)
{
    __shared__ float xv[3 * H];
    __shared__ float hid[H];
    int b = blockIdx.x, tid = threadIdx.x;
    int cnt = g_start[b + 1] - g_start[b];
    if (tid < 128) {
        int c = tid;
        float s = 0.f, m = -3.4e38f;
#pragma unroll
        for (int j = 0; j < RCH; ++j) {
            size_t o = ((size_t)b * RCH + j) * H + c;
            s += psum[o];
            m = fmaxf(m, pmax[o]);
        }
        float rc = 1.f / fmaxf((float)cnt, 1.f);
        xv[c]         = s * rc;
        xv[H + c]     = (cnt > 0) ? m : 0.f;
        xv[2 * H + c] = s;
    }
    __syncthreads();
    if (tid < 128) {
        float acc = 0.f;
        for (int k = 0; k < 3 * H; ++k)
            acc += xv[k] * W1[k * H + tid];
        hid[tid] = fmaxf(acc + b1[tid], 0.f);
    }
    __syncthreads();
    float acc = 0.f;
#pragma unroll 8
    for (int k = 0; k < H; ++k)
        acc += hid[k] * W2[k * T_OUT + tid];
    out[(size_t)b * T_OUT + tid] = acc + b2[tid];
}

extern "C" void kernel_launch(void* const* d_in, const int* in_sizes, int n_in,
                              void* d_out, int out_size, void* d_ws, size_t ws_size,
                              hipStream_t stream) {
    const float* node_feat = (const float*)d_in[0];
    const float* edge_feat = (const float*)d_in[1];
    const float* W_in  = (const float*)d_in[2];
    const float* b_in  = (const float*)d_in[3];
    const float* pre_W = (const float*)d_in[4];
    const float* pre_b = (const float*)d_in[5];
    const float* post_W = (const float*)d_in[6];
    const float* post_b = (const float*)d_in[7];
    const float* out_W1 = (const float*)d_in[8];
    const float* out_b1 = (const float*)d_in[9];
    const float* out_W2 = (const float*)d_in[10];
    const float* out_b2 = (const float*)d_in[11];
    const int* src = (const int*)d_in[12];
    const int* dst = (const int*)d_in[13];
    const int* n2g = (const int*)d_in[14];

    int N = in_sizes[0] / NODE_DIM;
    int E = in_sizes[1] / EDGE_DIM;
    int B = out_size / T_OUT;
    float* out = (float*)d_out;

    float* ws = (float*)d_ws;
    float* h    = ws; ws += (size_t)N * H;
    float* invd = ws; ws += N;
    float* amp  = ws; ws += N;
    float* att  = ws; ws += N;
    float* psum = ws; ws += (size_t)B * RCH * H;
    float* pmax = ws; ws += (size_t)B * RCH * H;
    ws = (float*)(((uintptr_t)ws + 15) & ~(uintptr_t)15);
    unsigned short* h_bf  = (unsigned short*)ws;
    unsigned short* s_buf = h_bf  + (size_t)N * H;
    unsigned short* mx    = s_buf + (size_t)N * H;
    unsigned short* mn    = mx    + (size_t)N * H;
    unsigned short* Y1bf  = mn    + (size_t)N * H;
    unsigned short* Y2bf  = Y1bf  + (size_t)N * H;
    unsigned short* efs_bf = Y2bf + (size_t)N * H;
    unsigned short* EFW    = efs_bf + (size_t)E * EDGE_DIM;
    short* wf_post_all = (short*)(EFW + (size_t)E * H);
    short* wf_y_all    = wf_post_all + (size_t)L_DEPTH * POST_FRAGS * 8;
    short* wf_ef_all   = wf_y_all + (size_t)L_DEPTH * Y_FRAGS * 8;
    short* wf_in       = wf_ef_all + (size_t)L_DEPTH * EF_FRAGS * 8;
    int* deg_i     = (int*)(wf_in + (size_t)IN_FRAGS * 8);
    int* row_start = deg_i + N;
    int* cursor    = row_start + N + 1;
    int* es_src    = cursor + N;
    int* es_eid    = es_src + E;
    int* g_start   = es_eid + E;   // B+1 ints

    int nPostBlocks = (N + 31) / 32;
    int nEfBlocks   = (E + 255) / 256;
    int nYBlocks    = (N + 63) / 64;
    int nHistBlocks = (E + 255) / 256;
    int nWinBlocks  = (IN_FRAGS + 255) / 256;
    int nSortBlocks = (E + 255) / 256;
    int nWconvBlocks = (L_DEPTH * (POST_FRAGS + Y_FRAGS + EF_FRAGS) + 255) / 256;
    int nMlpBlocks  = (N + 63) / 64;
    int nEfsBlocks  = ((size_t)E * 4 + 255) / 256;
    int nScalBlocks = (N + 255) / 256;
    int nGbBlocks   = (N + 1 + 255) / 256;

    // pre1: degree histogram + W_in fragment conversion (fat)
    hipMemsetAsync(deg_i, 0, (size_t)N * sizeof(int), stream);
    k_pre1<<<nHistBlocks + nWinBlocks, 256, 0, stream>>>(
        dst, deg_i, E, W_in, wf_in, nHistBlocks);

    // scan (single block)
    k_scan<<<1, 1024, 0, stream>>>(deg_i, row_start, cursor, N);

    // pre2: sort-scatter + all-layer weight conversion + MFMA input MLP (fat)
    k_pre2<<<nSortBlocks + nWconvBlocks + nMlpBlocks, 256, 0, stream>>>(
        src, dst, cursor, es_src, es_eid, E,
        pre_W, post_W, wf_y_all, wf_post_all, wf_ef_all,
        node_feat, b_in, wf_in, h, h_bf, N, nSortBlocks, nWconvBlocks);

    // pre3: ef permute + scalers + graph bounds (fat)
    k_pre3<<<nEfsBlocks + nScalBlocks + nGbBlocks, 256, 0, stream>>>(
        edge_feat, es_eid, efs_bf, E, deg_i, invd, amp, att, N,
        n2g, g_start, B, nEfsBlocks, nScalBlocks);

    // fat: layer-0 Y GEMM + layer-0 efw in one dispatch
    k_y0_fat<<<nYBlocks + nEfBlocks, 256, 0, stream>>>(
        h_bf, wf_y_all, Y1bf, Y2bf, N, efs_bf, wf_ef_all, EFW, E, nYBlocks);

    for (int l = 0; l < L_DEPTH; ++l) {
        k_edge_agg<<<(N + 3) / 4, 256, 0, stream>>>(
            Y1bf, Y2bf, EFW, pre_b + (size_t)l * H,
            es_src, row_start, s_buf, mx, mn, N);
        int doY = (l < L_DEPTH - 1) ? 1 : 0;
        int grid = nPostBlocks + (doY ? nEfBlocks : 0);
        k_post_fat<<<grid, 256, 0, stream>>>(
            h, h_bf, s_buf, mx, mn, invd, amp, att,
            wf_post_all + (size_t)l * POST_FRAGS * 8, post_b + (size_t)l * H,
            doY ? (wf_y_all + (size_t)(l + 1) * Y_FRAGS * 8) : wf_y_all,
            Y1bf, Y2bf, doY, N,
            efs_bf, doY ? (wf_ef_all + (size_t)(l + 1) * EF_FRAGS * 8) : wf_ef_all,
            EFW, E, nPostBlocks);
    }

    // two-stage readout (no atomics; n2g is sorted) + final MLP
    k_readout_part<<<B * RCH, 256, 0, stream>>>(h, g_start, psum, pmax, B);
    k_readout_final2<<<B, 256, 0, stream>>>(psum, pmax, g_start,
                                            out_W1, out_b1, out_W2, out_b2, out);
}